// Round 1
// baseline (609.597 us; speedup 1.0000x reference)
//
#include <hip/hip_runtime.h>
#include <stdint.h>

// QuantizedLinear: x[8,512,4096] fp32, W[11008,4096] int8-in-int32, scale[11008] fp32
#define M_DIM 4096
#define N_DIM 11008
#define K_DIM 4096

typedef int i32x4 __attribute__((ext_vector_type(4)));

// async global->LDS, 16 bytes/lane. LDS dest = wave-uniform base + lane*16.
static __device__ __forceinline__ void direct_load16(const void* gptr, void* ldsptr) {
    __builtin_amdgcn_global_load_lds(
        (const __attribute__((address_space(1))) void*)gptr,
        (__attribute__((address_space(3))) void*)ldsptr,
        16, 0, 0);
}

// ---- W: int32 in [-127,127] -> int8, 4 elems/thread, coalesced both sides
__global__ __launch_bounds__(256) void cvt_w_kernel(const int* __restrict__ w,
                                                    int8_t* __restrict__ o) {
    int t = blockIdx.x * 256 + threadIdx.x;
    const int4* w4 = (const int4*)w;
    int4 a = w4[t];
    ((unsigned*)o)[t] = (a.x & 255) | ((a.y & 255) << 8) | ((a.z & 255) << 16) | (a.w << 24);
}

// ---- x: fp32 -> int8 with per-row absmax scale --------------------------
__global__ __launch_bounds__(256) void quant_x_kernel(const float* __restrict__ x,
                                                      int8_t* __restrict__ xq,
                                                      float* __restrict__ xs) {
    __shared__ float wmax[4];
    const int row = blockIdx.x;
    const int t = threadIdx.x;
    const float4* xr = (const float4*)(x + (size_t)row * K_DIM);

    float4 v[4];
    float am = 0.0f;
#pragma unroll
    for (int p = 0; p < 4; p++) {
        v[p] = xr[p * 256 + t];
        am = fmaxf(am, fmaxf(fmaxf(fabsf(v[p].x), fabsf(v[p].y)),
                             fmaxf(fabsf(v[p].z), fabsf(v[p].w))));
    }
#pragma unroll
    for (int o = 32; o > 0; o >>= 1)
        am = fmaxf(am, __shfl_xor(am, o));
    if ((t & 63) == 0) wmax[t >> 6] = am;
    __syncthreads();
    am = fmaxf(fmaxf(wmax[0], wmax[1]), fmaxf(wmax[2], wmax[3]));

    const float inv = 127.0f / am;
    int* oq = (int*)(xq + (size_t)row * K_DIM);
#pragma unroll
    for (int p = 0; p < 4; p++) {
        int qa = (int)rintf(v[p].x * inv);
        int qb = (int)rintf(v[p].y * inv);
        int qc = (int)rintf(v[p].z * inv);
        int qd = (int)rintf(v[p].w * inv);
        oq[p * 256 + t] = (qa & 255) | ((qb & 255) << 8) | ((qc & 255) << 16) | (qd << 24);
    }
    if (t == 0) xs[row] = am * (1.0f / 127.0f);
}

// ---- GEMM: C = (Aq . Bq^T) * xs[m] * ws[n] ------------------------------
// 256x256 tile, 512 thr = 8 waves (2M x 4N), BK=64 i8, 4 LDS buffers,
// depth-3 prefetch with counted vmcnt(8) (never drains in main loop),
// ONE barrier per K-tile. XOR chunk swizzle (slot = chunk ^ ((row>>1)&3))
// applied on pre-swizzled global source + ds_read side (involution).
//
// Race-freedom: group t reads buf t&3 (reads drained by MFMA data-dep
// before the group-end barrier). Tile t+3 staged during group t writes buf
// (t+3)&3, which is only read by group t+3 — groups t..t+2 read bufs
// t&3,(t+1)&3,(t+2)&3, all distinct (4 buffers). vmcnt(8) at group-t end
// forces tile t+1 complete (own loads) + barrier publishes other waves'.

#define NT (K_DIM / 64)   // 64 K-tiles

__global__ __launch_bounds__(512, 2) void gemm_i8_kernel(
    const int8_t* __restrict__ A,     // [M][K] i8
    const int8_t* __restrict__ B,     // [N][K] i8
    const float* __restrict__ xs,     // [M]
    const float* __restrict__ ws,     // [N]
    float* __restrict__ C)            // [M][N] fp32
{
    __shared__ __align__(16) int8_t As[4][256 * 64];   // 64 KiB
    __shared__ __align__(16) int8_t Bs[4][256 * 64];   // 64 KiB

    const int tid  = threadIdx.x;
    const int lane = tid & 63;
    const int wave = tid >> 6;         // 0..7
    const int wm   = wave >> 2;        // 0..1 -> 128 rows each
    const int wn   = wave & 3;         // 0..3 -> 64 cols each
    const int quad = lane >> 4;
    const int r16  = lane & 15;

    // T1: XCD-aware bijective swizzle. grid = 16 x 43 = 688 = 8 * 86 exactly.
    const int orig = blockIdx.x + (blockIdx.y << 4);
    const int work = (orig & 7) * 86 + (orig >> 3);
    const int m0 = (work & 15) * 256;
    const int n0 = (work >> 4) * 256;

    // staging: thread t -> LDS row t>>2 (+128 for 2nd load), physical slot t&3.
    // physical slot p of row r holds logical chunk p ^ ((r>>1)&3), so the
    // global source column is pre-swizzled with the same XOR.
    const int srow   = tid >> 2;                       // 0..127
    const int schunk = (tid & 3) ^ ((tid >> 3) & 3);   // (tid>>3)&3 == f(row)
    const int8_t* gA = A + (size_t)(m0 + srow) * K_DIM + schunk * 16;
    const int8_t* gB = B + (size_t)(n0 + srow) * K_DIM + schunk * 16;
    const size_t half2 = (size_t)128 * K_DIM;          // rows 128..255
    const int wb = wave * 1024;                        // wave-uniform LDS base

    // read side: logical chunk = quad, physical = quad ^ ((row>>1)&3);
    // row = (16-aligned base) + r16  =>  f(row) = (r16>>1)&3
    const int fsw   = (r16 >> 1) & 3;
    const int a_off = (wm * 128 + r16) * 64 + ((quad ^ fsw) * 16);  // + i*1024
    const int b_off = (wn * 64  + r16) * 64 + ((quad ^ fsw) * 16);  // + j*1024

    i32x4 acc[8][4];
#pragma unroll
    for (int i = 0; i < 8; i++)
#pragma unroll
        for (int j = 0; j < 4; j++) acc[i][j] = (i32x4)(0);

#define STAGE(t) do {                                                        \
        char* _la = (char*)As[(t) & 3] + wb;                                 \
        char* _lb = (char*)Bs[(t) & 3] + wb;                                 \
        const size_t _ko = (size_t)(t) * 64;                                 \
        direct_load16(gA + _ko,         _la);                                \
        direct_load16(gA + _ko + half2, _la + 8192);                         \
        direct_load16(gB + _ko,         _lb);                                \
        direct_load16(gB + _ko + half2, _lb + 8192);                         \
    } while (0)

#define COMPUTE(t) do {                                                      \
        const int8_t* _as = As[(t) & 3];                                     \
        const int8_t* _bs = Bs[(t) & 3];                                     \
        i32x4 af[8], bf[4];                                                  \
        _Pragma("unroll")                                                    \
        for (int _i = 0; _i < 8; _i++)                                       \
            af[_i] = *(const i32x4*)(_as + a_off + _i * 1024);               \
        _Pragma("unroll")                                                    \
        for (int _j = 0; _j < 4; _j++)                                       \
            bf[_j] = *(const i32x4*)(_bs + b_off + _j * 1024);               \
        __builtin_amdgcn_s_setprio(1);                                       \
        _Pragma("unroll")                                                    \
        for (int _i = 0; _i < 8; _i++)                                       \
            _Pragma("unroll")                                                \
            for (int _j = 0; _j < 4; _j++)                                   \
                acc[_i][_j] = __builtin_amdgcn_mfma_i32_16x16x64_i8(         \
                    af[_i], bf[_j], acc[_i][_j], 0, 0, 0);                   \
        __builtin_amdgcn_s_setprio(0);                                       \
    } while (0)

    // prologue: stage tiles 0..2; need tile 0 complete (tiles 1,2 = 8 in flight)
    STAGE(0); STAGE(1); STAGE(2);
    asm volatile("s_waitcnt vmcnt(8)" ::: "memory");
    __builtin_amdgcn_s_barrier();
    asm volatile("" ::: "memory");

    for (int t = 0; t < NT - 3; ++t) {
        STAGE(t + 3);
        COMPUTE(t);
        // allow tiles t+2,t+3 (8 loads) in flight; forces tile t+1 complete
        asm volatile("s_waitcnt vmcnt(8)" ::: "memory");
        __builtin_amdgcn_s_barrier();
        asm volatile("" ::: "memory");
    }
    // epilogue tiles: drain 4 -> 0
    COMPUTE(NT - 3);
    asm volatile("s_waitcnt vmcnt(4)" ::: "memory");
    __builtin_amdgcn_s_barrier();
    asm volatile("" ::: "memory");
    COMPUTE(NT - 2);
    asm volatile("s_waitcnt vmcnt(0)" ::: "memory");
    __builtin_amdgcn_s_barrier();
    asm volatile("" ::: "memory");
    COMPUTE(NT - 1);

#undef STAGE
#undef COMPUTE

    // epilogue: fp32 rescale by xs[m]*ws[n]; C/D frag: col=r16, row=quad*4+r
#pragma unroll
    for (int i = 0; i < 8; i++) {
        const int mrow = m0 + wm * 128 + i * 16 + quad * 4;
        float rsc[4];
#pragma unroll
        for (int r = 0; r < 4; r++) rsc[r] = xs[mrow + r];
#pragma unroll
        for (int j = 0; j < 4; j++) {
            const int n = n0 + wn * 64 + j * 16 + r16;
            const float s = ws[n];
#pragma unroll
            for (int r = 0; r < 4; r++)
                C[(size_t)(mrow + r) * N_DIM + n] = (float)acc[i][j][r] * s * rsc[r];
        }
    }
}

// ---- launcher ------------------------------------------------------------

extern "C" void kernel_launch(void* const* d_in, const int* in_sizes, int n_in,
                              void* d_out, int out_size, void* d_ws, size_t ws_size,
                              hipStream_t stream) {
    const float* x       = (const float*)d_in[0];   // [4096][4096]
    const int*   w_int   = (const int*)d_in[1];     // [11008][4096]
    const float* w_scale = (const float*)d_in[2];   // [11008]
    float*       out     = (float*)d_out;           // [4096][11008]

    // ws layout: Wq i8 (45,088,768 B) | Xq i8 (16,777,216 B) | xs f32 (16,384 B)
    int8_t* wq = (int8_t*)d_ws;
    int8_t* xq = (int8_t*)((char*)d_ws + (size_t)N_DIM * K_DIM);
    float*  xs = (float*)((char*)d_ws + (size_t)N_DIM * K_DIM + (size_t)M_DIM * K_DIM);

    cvt_w_kernel<<<dim3(N_DIM * K_DIM / 4 / 256), dim3(256), 0, stream>>>(w_int, wq);
    quant_x_kernel<<<dim3(M_DIM), dim3(256), 0, stream>>>(x, xq, xs);
    gemm_i8_kernel<<<dim3(M_DIM / 256, N_DIM / 256), dim3(512), 0, stream>>>(xq, wq, xs, w_scale, out);
}

// Round 2
// 555.628 us; speedup vs baseline: 1.0971x; 1.0971x over previous
//
#include <hip/hip_runtime.h>
#include <stdint.h>

// QuantizedLinear: x[8,512,4096] fp32, W[11008,4096] int8-in-int32, scale[11008] fp32
#define M_DIM 4096
#define N_DIM 11008
#define K_DIM 4096

typedef int i32x4 __attribute__((ext_vector_type(4)));

// async global->LDS, 16 bytes/lane. LDS dest = wave-uniform base + lane*16.
static __device__ __forceinline__ void direct_load16(const void* gptr, void* ldsptr) {
    __builtin_amdgcn_global_load_lds(
        (const __attribute__((address_space(1))) void*)gptr,
        (__attribute__((address_space(3))) void*)ldsptr,
        16, 0, 0);
}

// ---- W: int32 in [-127,127] -> int8, 4 elems/thread, coalesced both sides
__global__ __launch_bounds__(256) void cvt_w_kernel(const int* __restrict__ w,
                                                    int8_t* __restrict__ o) {
    int t = blockIdx.x * 256 + threadIdx.x;
    const int4* w4 = (const int4*)w;
    int4 a = w4[t];
    ((unsigned*)o)[t] = (a.x & 255) | ((a.y & 255) << 8) | ((a.z & 255) << 16) | (a.w << 24);
}

// ---- x: fp32 -> int8 with per-row absmax scale --------------------------
__global__ __launch_bounds__(256) void quant_x_kernel(const float* __restrict__ x,
                                                      int8_t* __restrict__ xq,
                                                      float* __restrict__ xs) {
    __shared__ float wmax[4];
    const int row = blockIdx.x;
    const int t = threadIdx.x;
    const float4* xr = (const float4*)(x + (size_t)row * K_DIM);

    float4 v[4];
    float am = 0.0f;
#pragma unroll
    for (int p = 0; p < 4; p++) {
        v[p] = xr[p * 256 + t];
        am = fmaxf(am, fmaxf(fmaxf(fabsf(v[p].x), fabsf(v[p].y)),
                             fmaxf(fabsf(v[p].z), fabsf(v[p].w))));
    }
#pragma unroll
    for (int o = 32; o > 0; o >>= 1)
        am = fmaxf(am, __shfl_xor(am, o));
    if ((t & 63) == 0) wmax[t >> 6] = am;
    __syncthreads();
    am = fmaxf(fmaxf(wmax[0], wmax[1]), fmaxf(wmax[2], wmax[3]));

    const float inv = 127.0f / am;
    int* oq = (int*)(xq + (size_t)row * K_DIM);
#pragma unroll
    for (int p = 0; p < 4; p++) {
        int qa = (int)rintf(v[p].x * inv);
        int qb = (int)rintf(v[p].y * inv);
        int qc = (int)rintf(v[p].z * inv);
        int qd = (int)rintf(v[p].w * inv);
        oq[p * 256 + t] = (qa & 255) | ((qb & 255) << 8) | ((qc & 255) << 16) | (qd << 24);
    }
    if (t == 0) xs[row] = am * (1.0f / 127.0f);
}

// ---- GEMM: C = (Aq . Bq^T) * xs[m] * ws[n] ------------------------------
// 256x256 tile, 512 thr = 8 waves (2M x 4N). 8-phase schedule (m201 port):
// BK=64 i8, 4 LDS buffers (tile t -> buf t&3). Iter i covers tiles 4i..4i+3,
// 2 phases per tile (i-half h). Per phase: 8 ds_read_b128 + stage ONE
// matrix-unit (16KB, 2 gload_lds) + barrier + 16 MFMA (setprio) + barrier.
// vmcnt(8) before the trailing barrier of ODD phases only: keeps 4 units
// (8 loads) in flight, forces exactly the unit pair read 2 phases later.
//
// Stage slots (iter i): p0:A(4i+3)->b3  p1:B(4i+3)->b3  p2:A(4i+4)->b0
// p3:B(4i+4)->b0  p4:A(4i+5)->b1  p5:B(4i+5)->b1  p6:A(4i+6)->b2
// p7:B(4i+6)->b2.  Each target region's last reader finished one phase
// before the stage issues (reads of buf b end at that buf's h1 phase).
// Tail: tile index clamps to 63 (L2-hot; writes land only in regions
// never read again). XOR chunk swizzle (phys = chunk ^ ((row>>1)&3)) on
// pre-swizzled global source + ds_read side — measured 0 bank conflicts.

__global__ __launch_bounds__(512, 2) void gemm_i8_kernel(
    const int8_t* __restrict__ A,     // [M][K] i8
    const int8_t* __restrict__ B,     // [N][K] i8
    const float* __restrict__ xs,     // [M]
    const float* __restrict__ ws,     // [N]
    float* __restrict__ C)            // [M][N] fp32
{
    __shared__ __align__(16) int8_t As[4][256 * 64];   // 64 KiB
    __shared__ __align__(16) int8_t Bs[4][256 * 64];   // 64 KiB

    const int tid  = threadIdx.x;
    const int lane = tid & 63;
    const int wave = tid >> 6;         // 0..7
    const int wm   = wave >> 2;        // 0..1 -> 128 rows each
    const int wn   = wave & 3;         // 0..3 -> 64 cols each
    const int quad = lane >> 4;
    const int r16  = lane & 15;

    // T1: XCD-aware bijective swizzle. grid = 16 x 43 = 688 = 8 * 86 exactly.
    const int orig = blockIdx.x + (blockIdx.y << 4);
    const int work = (orig & 7) * 86 + (orig >> 3);
    const int m0 = (work & 15) * 256;
    const int n0 = (work >> 4) * 256;

    // staging: thread t -> LDS row t>>2 (+128 for 2nd load), physical slot t&3.
    const int srow   = tid >> 2;                       // 0..127
    const int schunk = (tid & 3) ^ ((tid >> 3) & 3);   // pre-swizzled source chunk
    const int8_t* gA = A + (size_t)(m0 + srow) * K_DIM + schunk * 16;
    const int8_t* gB = B + (size_t)(n0 + srow) * K_DIM + schunk * 16;
    const size_t half2 = (size_t)128 * K_DIM;          // rows 128..255
    const int wb = wave * 1024;                        // wave-uniform LDS base

    // read side: logical chunk = quad, physical = quad ^ ((row>>1)&3)
    const int fsw   = (r16 >> 1) & 3;
    const int a_off = (wm * 128 + r16) * 64 + ((quad ^ fsw) * 16);  // + i*1024
    const int b_off = (wn * 64  + r16) * 64 + ((quad ^ fsw) * 16);  // + j*1024

    i32x4 acc[8][4];
#pragma unroll
    for (int i = 0; i < 8; i++)
#pragma unroll
        for (int j = 0; j < 4; j++) acc[i][j] = (i32x4)(0);

#define STAGE_A(t, buf) do {                                                  \
        direct_load16(gA + (size_t)(t) * 64,         (char*)As[buf] + wb);    \
        direct_load16(gA + (size_t)(t) * 64 + half2, (char*)As[buf] + wb + 8192); \
    } while (0)
#define STAGE_B(t, buf) do {                                                  \
        direct_load16(gB + (size_t)(t) * 64,         (char*)Bs[buf] + wb);    \
        direct_load16(gB + (size_t)(t) * 64 + half2, (char*)Bs[buf] + wb + 8192); \
    } while (0)

#define PHASE(rbuf, h, STAGE_STMT, DOVM) do {                                 \
        const int8_t* _as = As[rbuf];                                         \
        const int8_t* _bs = Bs[rbuf];                                         \
        i32x4 af[4], bf[4];                                                   \
        _Pragma("unroll")                                                     \
        for (int _i = 0; _i < 4; _i++)                                        \
            af[_i] = *(const i32x4*)(_as + a_off + ((h) * 4 + _i) * 1024);    \
        _Pragma("unroll")                                                     \
        for (int _j = 0; _j < 4; _j++)                                        \
            bf[_j] = *(const i32x4*)(_bs + b_off + _j * 1024);                \
        STAGE_STMT;                                                           \
        __builtin_amdgcn_s_barrier();                                         \
        __builtin_amdgcn_s_setprio(1);                                        \
        _Pragma("unroll")                                                     \
        for (int _i = 0; _i < 4; _i++)                                        \
            _Pragma("unroll")                                                 \
            for (int _j = 0; _j < 4; _j++)                                    \
                acc[(h) * 4 + _i][_j] = __builtin_amdgcn_mfma_i32_16x16x64_i8(\
                    af[_i], bf[_j], acc[(h) * 4 + _i][_j], 0, 0, 0);          \
        __builtin_amdgcn_s_setprio(0);                                        \
        if (DOVM) asm volatile("s_waitcnt vmcnt(8)" ::: "memory");            \
        __builtin_amdgcn_s_barrier();                                         \
    } while (0)

    // prologue: 6 units (12 loads); vmcnt(8) forces T0's 4 loads complete
    STAGE_A(0, 0); STAGE_B(0, 0);
    STAGE_A(1, 1); STAGE_B(1, 1);
    STAGE_A(2, 2); STAGE_B(2, 2);
    asm volatile("s_waitcnt vmcnt(8)" ::: "memory");
    __builtin_amdgcn_s_barrier();

    for (int i = 0; i < 16; ++i) {
        const int t3 = 4 * i + 3;                              // <= 63 always
        const int t4 = (4 * i + 4 > 63) ? 63 : 4 * i + 4;      // clamp tail
        const int t5 = (4 * i + 5 > 63) ? 63 : 4 * i + 5;
        const int t6 = (4 * i + 6 > 63) ? 63 : 4 * i + 6;
        PHASE(0, 0, STAGE_A(t3, 3), 0);
        PHASE(0, 1, STAGE_B(t3, 3), 1);
        PHASE(1, 0, STAGE_A(t4, 0), 0);
        PHASE(1, 1, STAGE_B(t4, 0), 1);
        PHASE(2, 0, STAGE_A(t5, 1), 0);
        PHASE(2, 1, STAGE_B(t5, 1), 1);
        PHASE(3, 0, STAGE_A(t6, 2), 0);
        PHASE(3, 1, STAGE_B(t6, 2), 1);
    }

#undef PHASE
#undef STAGE_A
#undef STAGE_B

    // epilogue: fp32 rescale by xs[m]*ws[n]; C/D frag: col=r16, row=quad*4+r
#pragma unroll
    for (int i = 0; i < 8; i++) {
        const int mrow = m0 + wm * 128 + i * 16 + quad * 4;
        float rsc[4];
#pragma unroll
        for (int r = 0; r < 4; r++) rsc[r] = xs[mrow + r];
#pragma unroll
        for (int j = 0; j < 4; j++) {
            const int n = n0 + wn * 64 + j * 16 + r16;
            const float s = ws[n];
#pragma unroll
            for (int r = 0; r < 4; r++)
                C[(size_t)(mrow + r) * N_DIM + n] = (float)acc[i][j][r] * s * rsc[r];
        }
    }
}

// ---- launcher ------------------------------------------------------------

extern "C" void kernel_launch(void* const* d_in, const int* in_sizes, int n_in,
                              void* d_out, int out_size, void* d_ws, size_t ws_size,
                              hipStream_t stream) {
    const float* x       = (const float*)d_in[0];   // [4096][4096]
    const int*   w_int   = (const int*)d_in[1];     // [11008][4096]
    const float* w_scale = (const float*)d_in[2];   // [11008]
    float*       out     = (float*)d_out;           // [4096][11008]

    // ws layout: Wq i8 (45,088,768 B) | Xq i8 (16,777,216 B) | xs f32 (16,384 B)
    int8_t* wq = (int8_t*)d_ws;
    int8_t* xq = (int8_t*)((char*)d_ws + (size_t)N_DIM * K_DIM);
    float*  xs = (float*)((char*)d_ws + (size_t)N_DIM * K_DIM + (size_t)M_DIM * K_DIM);

    cvt_w_kernel<<<dim3(N_DIM * K_DIM / 4 / 256), dim3(256), 0, stream>>>(w_int, wq);
    quant_x_kernel<<<dim3(M_DIM), dim3(256), 0, stream>>>(x, xq, xs);
    gemm_i8_kernel<<<dim3(M_DIM / 256, N_DIM / 256), dim3(512), 0, stream>>>(xq, wq, xs, w_scale, out);
}

// Round 4
// 541.982 us; speedup vs baseline: 1.1248x; 1.0252x over previous
//
#include <hip/hip_runtime.h>
#include <stdint.h>

// QuantizedLinear: x[8,512,4096] fp32, W[11008,4096] int8-in-int32, scale[11008] fp32
#define M_DIM 4096
#define N_DIM 11008
#define K_DIM 4096

typedef int i32x4 __attribute__((ext_vector_type(4)));

// async global->LDS, 16 bytes/lane. LDS dest = wave-uniform base + lane*16.
static __device__ __forceinline__ void direct_load16(const void* gptr, void* ldsptr) {
    __builtin_amdgcn_global_load_lds(
        (const __attribute__((address_space(1))) void*)gptr,
        (__attribute__((address_space(3))) void*)ldsptr,
        16, 0, 0);
}

// ---- W: int32 in [-127,127] -> int8, 4 elems/thread, coalesced both sides
__global__ __launch_bounds__(256) void cvt_w_kernel(const int* __restrict__ w,
                                                    int8_t* __restrict__ o) {
    int t = blockIdx.x * 256 + threadIdx.x;
    const int4* w4 = (const int4*)w;
    int4 a = w4[t];
    ((unsigned*)o)[t] = (a.x & 255) | ((a.y & 255) << 8) | ((a.z & 255) << 16) | (a.w << 24);
}

// ---- x: fp32 -> int8 with per-row absmax scale --------------------------
__global__ __launch_bounds__(256) void quant_x_kernel(const float* __restrict__ x,
                                                      int8_t* __restrict__ xq,
                                                      float* __restrict__ xs) {
    __shared__ float wmax[4];
    const int row = blockIdx.x;
    const int t = threadIdx.x;
    const float4* xr = (const float4*)(x + (size_t)row * K_DIM);

    float4 v[4];
    float am = 0.0f;
#pragma unroll
    for (int p = 0; p < 4; p++) {
        v[p] = xr[p * 256 + t];
        am = fmaxf(am, fmaxf(fmaxf(fabsf(v[p].x), fabsf(v[p].y)),
                             fmaxf(fabsf(v[p].z), fabsf(v[p].w))));
    }
#pragma unroll
    for (int o = 32; o > 0; o >>= 1)
        am = fmaxf(am, __shfl_xor(am, o));
    if ((t & 63) == 0) wmax[t >> 6] = am;
    __syncthreads();
    am = fmaxf(fmaxf(wmax[0], wmax[1]), fmaxf(wmax[2], wmax[3]));

    const float inv = 127.0f / am;
    int* oq = (int*)(xq + (size_t)row * K_DIM);
#pragma unroll
    for (int p = 0; p < 4; p++) {
        int qa = (int)rintf(v[p].x * inv);
        int qb = (int)rintf(v[p].y * inv);
        int qc = (int)rintf(v[p].z * inv);
        int qd = (int)rintf(v[p].w * inv);
        oq[p * 256 + t] = (qa & 255) | ((qb & 255) << 8) | ((qc & 255) << 16) | (qd << 24);
    }
    if (t == 0) xs[row] = am * (1.0f / 127.0f);
}

// ---- GEMM: C = (Aq . Bq^T) * xs[m] * ws[n] ------------------------------
// 256x256 tile, 512 thr = 8 waves (2M x 4N). Software-pipelined 2-phase/tile
// schedule: register ping-pong (afX/afY per phase, bfA/bfB per tile) so each
// phase's ds_reads load the NEXT phase's fragments while the MFMA cluster
// runs on the current bank. ONE barrier + vmcnt(4) per phase. B frags read
// once per tile (2+2 split across phases): 12 ds_read_b128/tile/wave.
//
// Staging: 4 LDS buffers (tile t -> buf t&3), depth-3: tile t's phases stage
// tile t+3 (A in h0, B in h1). vmcnt(4) at each phase end leaves only the
// current+previous phase's units (4 loads) in flight => tile t+2 is forced
// complete by end of (t,h1), one phase before its first read at (t+1,h0).
// Prologue stages tiles 0-2, vmcnt(4) forces tiles 0,1 complete (tile-1 B is
// read-ahead during (0,h0)). Tail stages clamp to tile 63 and land in buffers
// whose readers already finished (dummy, race-free). XOR chunk swizzle
// (phys = chunk ^ ((row>>1)&3)) on pre-swizzled source + read side: 0 bank
// conflicts measured.

__global__ __launch_bounds__(512, 2) void gemm_i8_kernel(
    const int8_t* __restrict__ A,     // [M][K] i8
    const int8_t* __restrict__ B,     // [N][K] i8
    const float* __restrict__ xs,     // [M]
    const float* __restrict__ ws,     // [N]
    float* __restrict__ C)            // [M][N] fp32
{
    __shared__ __align__(16) int8_t As[4][256 * 64];   // 64 KiB
    __shared__ __align__(16) int8_t Bs[4][256 * 64];   // 64 KiB

    const int tid  = threadIdx.x;
    const int lane = tid & 63;
    const int wave = tid >> 6;         // 0..7
    const int wm   = wave >> 2;        // 0..1 -> 128 rows each
    const int wn   = wave & 3;         // 0..3 -> 64 cols each
    const int quad = lane >> 4;
    const int r16  = lane & 15;

    // T1: XCD-aware bijective swizzle. grid = 16 x 43 = 688 = 8 * 86 exactly.
    const int orig = blockIdx.x + (blockIdx.y << 4);
    const int work = (orig & 7) * 86 + (orig >> 3);
    const int m0 = (work & 15) * 256;
    const int n0 = (work >> 4) * 256;

    // staging: thread t -> LDS row t>>2 (+128 for 2nd load), physical slot t&3.
    const int srow   = tid >> 2;                       // 0..127
    const int schunk = (tid & 3) ^ ((tid >> 3) & 3);   // pre-swizzled source chunk
    const int8_t* gA = A + (size_t)(m0 + srow) * K_DIM + schunk * 16;
    const int8_t* gB = B + (size_t)(n0 + srow) * K_DIM + schunk * 16;
    const size_t half2 = (size_t)128 * K_DIM;          // rows 128..255
    const int wb = wave * 1024;                        // wave-uniform LDS base

    // read side: logical chunk = quad, physical = quad ^ ((row>>1)&3)
    const int fsw   = (r16 >> 1) & 3;
    const int a_off = (wm * 128 + r16) * 64 + ((quad ^ fsw) * 16);  // + i*1024
    const int b_off = (wn * 64  + r16) * 64 + ((quad ^ fsw) * 16);  // + j*1024

    i32x4 acc[8][4];
#pragma unroll
    for (int i = 0; i < 8; i++)
#pragma unroll
        for (int j = 0; j < 4; j++) acc[i][j] = (i32x4)(0);

    i32x4 afX[4], afY[4], bfA[4], bfB[4];

#define STAGE_A(t, buf) do {                                                  \
        direct_load16(gA + (size_t)(t) * 64,         (char*)As[buf] + wb);    \
        direct_load16(gA + (size_t)(t) * 64 + half2, (char*)As[buf] + wb + 8192); \
    } while (0)
#define STAGE_B(t, buf) do {                                                  \
        direct_load16(gB + (size_t)(t) * 64,         (char*)Bs[buf] + wb);    \
        direct_load16(gB + (size_t)(t) * 64 + half2, (char*)Bs[buf] + wb + 8192); \
    } while (0)

// load A fragments fb..fb+3 of buffer buf into dst (next-phase prefetch)
#define LDA4(dst, buf, fb) do {                                               \
        const int8_t* _p = As[buf];                                           \
        _Pragma("unroll")                                                     \
        for (int _i = 0; _i < 4; _i++)                                        \
            dst[_i] = *(const i32x4*)(_p + a_off + ((fb) + _i) * 1024);       \
    } while (0)
// load B fragments j0, j0+1 of buffer buf into dst
#define LDB2(dst, buf, j0) do {                                               \
        const int8_t* _p = Bs[buf];                                           \
        dst[(j0)]     = *(const i32x4*)(_p + b_off + ((j0)) * 1024);          \
        dst[(j0) + 1] = *(const i32x4*)(_p + b_off + ((j0) + 1) * 1024);      \
    } while (0)
// MFMA cluster on current banks, then counted-vmcnt + single barrier
#define MM(AF, BF, H) do {                                                    \
        __builtin_amdgcn_s_setprio(1);                                        \
        _Pragma("unroll")                                                     \
        for (int _i = 0; _i < 4; _i++)                                        \
            _Pragma("unroll")                                                 \
            for (int _j = 0; _j < 4; _j++)                                    \
                acc[(H) * 4 + _i][_j] = __builtin_amdgcn_mfma_i32_16x16x64_i8(\
                    AF[_i], BF[_j], acc[(H) * 4 + _i][_j], 0, 0, 0);          \
        __builtin_amdgcn_s_setprio(0);                                        \
        asm volatile("s_waitcnt vmcnt(4)" ::: "memory");                      \
        __builtin_amdgcn_s_barrier();                                         \
    } while (0)

    // prologue: stage tiles 0,1,2; vmcnt(4) forces tiles 0,1 complete
    STAGE_A(0, 0); STAGE_B(0, 0);
    STAGE_A(1, 1); STAGE_B(1, 1);
    STAGE_A(2, 2); STAGE_B(2, 2);
    asm volatile("s_waitcnt vmcnt(4)" ::: "memory");
    __builtin_amdgcn_s_barrier();

    // initial fragments for (tile0, h0)
    LDA4(afX, 0, 0);
    LDB2(bfA, 0, 0); LDB2(bfA, 0, 2);

    for (int u = 0; u < 32; ++u) {
        const int t0 = 2 * u, t1 = t0 + 1;
        const int b0 = t0 & 3, b1 = t1 & 3, b2 = (t0 + 2) & 3;
        const int sb0 = (t0 + 3) & 3, sb1 = (t0 + 4) & 3;
        const int s0 = (t0 + 3 > 63) ? 63 : t0 + 3;
        const int s1 = (t0 + 4 > 63) ? 63 : t0 + 4;

        // (t0,h0): compute afX*bfA; prefetch afY=frags4-7(t0), bfB[0:1](t1)
        LDA4(afY, b0, 4); LDB2(bfB, b1, 0); STAGE_A(s0, sb0); MM(afX, bfA, 0);
        // (t0,h1): compute afY*bfA; prefetch afX=frags0-3(t1), bfB[2:3](t1)
        LDA4(afX, b1, 0); LDB2(bfB, b1, 2); STAGE_B(s0, sb0); MM(afY, bfA, 1);
        // (t1,h0): compute afX*bfB; prefetch afY=frags4-7(t1), bfA[0:1](t0+2)
        LDA4(afY, b1, 4); LDB2(bfA, b2, 0); STAGE_A(s1, sb1); MM(afX, bfB, 0);
        // (t1,h1): compute afY*bfB; prefetch afX=frags0-3(t0+2), bfA[2:3](t0+2)
        LDA4(afX, b2, 0); LDB2(bfA, b2, 2); STAGE_B(s1, sb1); MM(afY, bfB, 1);
    }

#undef MM
#undef LDB2
#undef LDA4
#undef STAGE_B
#undef STAGE_A

    // epilogue: fp32 rescale by xs[m]*ws[n]; C/D frag: col=r16, row=quad*4+r
#pragma unroll
    for (int i = 0; i < 8; i++) {
        const int mrow = m0 + wm * 128 + i * 16 + quad * 4;
        float rsc[4];
#pragma unroll
        for (int r = 0; r < 4; r++) rsc[r] = xs[mrow + r];
#pragma unroll
        for (int j = 0; j < 4; j++) {
            const int n = n0 + wn * 64 + j * 16 + r16;
            const float s = ws[n];
#pragma unroll
            for (int r = 0; r < 4; r++)
                C[(size_t)(mrow + r) * N_DIM + n] = (float)acc[i][j][r] * s * rsc[r];
        }
    }
}

// ---- launcher ------------------------------------------------------------

extern "C" void kernel_launch(void* const* d_in, const int* in_sizes, int n_in,
                              void* d_out, int out_size, void* d_ws, size_t ws_size,
                              hipStream_t stream) {
    const float* x       = (const float*)d_in[0];   // [4096][4096]
    const int*   w_int   = (const int*)d_in[1];     // [11008][4096]
    const float* w_scale = (const float*)d_in[2];   // [11008]
    float*       out     = (float*)d_out;           // [4096][11008]

    // ws layout: Wq i8 (45,088,768 B) | Xq i8 (16,777,216 B) | xs f32 (16,384 B)
    int8_t* wq = (int8_t*)d_ws;
    int8_t* xq = (int8_t*)((char*)d_ws + (size_t)N_DIM * K_DIM);
    float*  xs = (float*)((char*)d_ws + (size_t)N_DIM * K_DIM + (size_t)M_DIM * K_DIM);

    cvt_w_kernel<<<dim3(N_DIM * K_DIM / 4 / 256), dim3(256), 0, stream>>>(w_int, wq);
    quant_x_kernel<<<dim3(M_DIM), dim3(256), 0, stream>>>(x, xq, xs);
    gemm_i8_kernel<<<dim3(M_DIM / 256, N_DIM / 256), dim3(512), 0, stream>>>(xq, wq, xs, w_scale, out);
}